// Round 3
// baseline (323.496 us; speedup 1.0000x reference)
//
#include <hip/hip_runtime.h>

#define EG   16000   // graph edges
#define BB   32      // batch
#define SIZE 16000   // feature length (1000 blocks * 16)

// ---- kernel 1: write reparameterized bias into out, zero the kl scalar ----
__global__ __launch_bounds__(256) void init_out_kernel(
    const float* __restrict__ bm, const float* __restrict__ blv,
    const float* __restrict__ eb, float* __restrict__ out)
{
    int r = blockIdx.x * 256 + threadIdx.x;   // feature index
    int b = blockIdx.y;                        // batch index
    if (r < SIZE) {
        float bias = eb[r] * __expf(blv[r]) + bm[r];
        out[b * SIZE + r] = bias;
    }
    if (blockIdx.x == 0 && blockIdx.y == 0 && threadIdx.x == 0)
        out[BB * SIZE] = 0.0f;                 // kl scalar
}

// ---- kernel 2: one workgroup per edge, scatter with HW f32 atomics ----
// Edge e: for all b, j:  out[b, t0*16+j] += sum_i v[i][j] * x[b, t1*16+i]
// Compute phase keeps the proven conflict-free (b0=tid>>4, j=tid&15) layout.
// Epilogue remaps lanes through LDS to (b=tid&31, jh=tid>>5) so each wave's
// 64 atomics hit 32 distinct 64B lines (vs 4 before) -> parallel TCC channels.
__global__ __launch_bounds__(256) void edge_kernel(
    const float* __restrict__ wm, const float* __restrict__ wlv,
    const float* __restrict__ ew, const float* __restrict__ x,
    const int* __restrict__ rows, const int* __restrict__ cols,
    float* __restrict__ out)
{
    __shared__ float vt[256];        // vt[i*16+j] = sampled weight
    __shared__ float xs[512];        // xs[b*16+i] = x[b, t1*16+i]
    __shared__ float sacc[32 * 17];  // padded accumulator exchange (stride 17)

    int e    = blockIdx.x;
    int tid  = threadIdx.x;
    int base = e << 8;

    int t0 = rows[base] >> 4;   // rows[e*256] = t0*16 (uniform scalar load)
    int t1 = cols[base] >> 4;   // cols[e*256] = t1*16

    // values = eps_w * exp(log_var) + mean  (reparameterization sample)
    vt[tid] = ew[base + tid] * __expf(wlv[base + tid]) + wm[base + tid];

    int j  = tid & 15;
    int b0 = tid >> 4;          // 0..15
    int xb = t1 << 4;
    xs[tid]       = x[ b0        * SIZE + xb + j];   // coalesced 64B per 16 lanes
    xs[tid + 256] = x[(b0 + 16)  * SIZE + xb + j];
    __syncthreads();

    float acc0 = 0.f, acc1 = 0.f;
    #pragma unroll
    for (int i = 0; i < 16; ++i) {
        float vv = vt[(i << 4) + j];            // broadcast within j-group
        acc0 += vv * xs[((b0)      << 4) + i];  // broadcast
        acc1 += vv * xs[((b0 + 16) << 4) + i];
    }

    // ---- epilogue: exchange accumulators, spread atomics across lines ----
    sacc[ b0       * 17 + j] = acc0;   // ~2-way bank aliasing (free)
    sacc[(b0 + 16) * 17 + j] = acc1;
    __syncthreads();

    int bb = tid & 31;          // batch row 0..31 (distinct per lane in wave)
    int jh = tid >> 5;          // 0..7
    int r0 = t0 << 4;
    float a0 = sacc[bb * 17 + jh];       // stride 17: conflict-free
    float a1 = sacc[bb * 17 + jh + 8];
    // unsafeAtomicAdd -> global_atomic_add_f32 (HW f32 atomic, no CAS loop)
    unsafeAtomicAdd(&out[bb * SIZE + r0 + jh],     a0);
    unsafeAtomicAdd(&out[bb * SIZE + r0 + jh + 8], a1);
}

extern "C" void kernel_launch(void* const* d_in, const int* in_sizes, int n_in,
                              void* d_out, int out_size, void* d_ws, size_t ws_size,
                              hipStream_t stream) {
    const float* x   = (const float*)d_in[0];
    const float* wm  = (const float*)d_in[1];
    const float* wlv = (const float*)d_in[2];
    const float* bm  = (const float*)d_in[3];
    const float* blv = (const float*)d_in[4];
    const float* ew  = (const float*)d_in[5];
    const float* eb  = (const float*)d_in[6];
    const int* rows  = (const int*)d_in[7];
    const int* cols  = (const int*)d_in[8];
    float* out = (float*)d_out;

    init_out_kernel<<<dim3((SIZE + 255) / 256, BB), 256, 0, stream>>>(bm, blv, eb, out);
    edge_kernel<<<EG, 256, 0, stream>>>(wm, wlv, ew, x, rows, cols, out);
}

// Round 5
// 147.769 us; speedup vs baseline: 2.1892x; 2.1892x over previous
//
#include <hip/hip_runtime.h>

#define EG   16000   // graph edges
#define BB   32      // batch
#define SIZE 16000   // feature length (1000 blocks * 16)

typedef float f32x4 __attribute__((ext_vector_type(4)));  // native vec type:
// __builtin_nontemporal_load requires scalar/native-vector, not HIP_vector_type

// ---- kernel 1: write reparameterized bias into out, zero the kl scalar ----
__global__ __launch_bounds__(256) void init_out_kernel(
    const float* __restrict__ bm, const float* __restrict__ blv,
    const float* __restrict__ eb, float* __restrict__ out)
{
    int r = blockIdx.x * 256 + threadIdx.x;   // feature index
    int b = blockIdx.y;                        // batch index
    if (r < SIZE) {
        float bias = eb[r] * __expf(blv[r]) + bm[r];
        out[b * SIZE + r] = bias;
    }
    if (blockIdx.x == 0 && blockIdx.y == 0 && threadIdx.x == 0)
        out[BB * SIZE] = 0.0f;                 // kl scalar
}

// ---- kernel 2: 4 edges per workgroup, float4 loads, b128 LDS compute ----
// Edge e: for all b, j:  out[b, t0*16+j] += sum_i v[i*16+j] * x[b, t1*16+i]
// Epilogue = round-1 pattern (PROVEN): each wave's atomics are 16 consecutive
// dwords per line (TA coalesces to one line transaction), lines wave-private.
// DO NOT spread atomics across lines -- measured 6x regression (round 3).
__global__ __launch_bounds__(256) void edge_kernel(
    const float* __restrict__ wm, const float* __restrict__ wlv,
    const float* __restrict__ ew, const float* __restrict__ x,
    const int* __restrict__ rows, const int* __restrict__ cols,
    float* __restrict__ out)
{
    __shared__ float vtT[1024];   // [k][j*16+i]  transposed sampled weights
    __shared__ float xs[2048];    // [k][b*16+i]  x tiles (float4-stored)
    __shared__ int   st0[4];      // t0 per edge
    __shared__ int   st1[4];      // t1 per edge

    int tid = threadIdx.x;
    int grp = blockIdx.x;         // 4-edge group
    int E   = grp << 2;

    // edge block indices (8 broadcast loads total for the block)
    if (tid < 8) {
        int k = tid & 3;
        if (tid < 4) st1[k] = cols[(long)(E + k) << 8] >> 4;
        else         st0[k] = rows[(long)(E + k) << 8] >> 4;
    }

    // ---- weight stage: 3 x dwordx4 per thread, nontemporal (single-use) ----
    const f32x4* wm4  = (const f32x4*)wm;
    const f32x4* wlv4 = (const f32x4*)wlv;
    const f32x4* ew4  = (const f32x4*)ew;
    int qi = (grp << 8) + tid;                 // float4 index into NNZ arrays
    f32x4 m4 = __builtin_nontemporal_load(&wm4[qi]);
    f32x4 l4 = __builtin_nontemporal_load(&wlv4[qi]);
    f32x4 e4 = __builtin_nontemporal_load(&ew4[qi]);
    f32x4 v4;
    v4.x = e4.x * __expf(l4.x) + m4.x;
    v4.y = e4.y * __expf(l4.y) + m4.y;
    v4.z = e4.z * __expf(l4.z) + m4.z;
    v4.w = e4.w * __expf(l4.w) + m4.w;
    // transpose into vtT: this thread holds d = 4*tid .. 4*tid+3
    //   k = tid>>6, i = (tid>>2)&15, j0 = 4*(tid&3)
    {
        int k  = tid >> 6;
        int i  = (tid >> 2) & 15;
        int j0 = (tid & 3) << 2;
        int b  = (k << 8) + i;
        vtT[b + (j0    ) * 16] = v4.x;
        vtT[b + (j0 + 1) * 16] = v4.y;
        vtT[b + (j0 + 2) * 16] = v4.z;
        vtT[b + (j0 + 3) * 16] = v4.w;
    }
    __syncthreads();              // st0/st1 + vtT visible

    // ---- x stage: 2 x float4 per thread ----
    const f32x4* x4 = (const f32x4*)x;
    f32x4* xs4 = (f32x4*)xs;
    #pragma unroll
    for (int h = 0; h < 2; ++h) {
        int q   = tid + (h << 8);             // 0..511
        int k   = q >> 7;
        int rem = q & 127;
        int b   = rem >> 2;                    // batch 0..31
        int i4  = rem & 3;                     // float4 slot 0..3
        xs4[(k << 7) + (b << 2) + i4] =
            x4[b * (SIZE / 4) + (st1[k] << 2) + i4];
    }
    __syncthreads();

    // ---- compute: all b128 LDS reads ----
    int j  = tid & 15;
    int b0 = tid >> 4;            // 0..15
    const f32x4* vtT4 = (const f32x4*)vtT;
    float acc0[4], acc1[4];
    #pragma unroll
    for (int k = 0; k < 4; ++k) {
        float a0 = 0.f, a1 = 0.f;
        #pragma unroll
        for (int q = 0; q < 4; ++q) {
            f32x4 w  = vtT4[(k << 6) + (j << 2) + q];           // col j, i=4q..4q+3
            f32x4 xa = xs4[(k << 7) + (b0 << 2) + q];           // batch b0
            f32x4 xb = xs4[(k << 7) + ((b0 + 16) << 2) + q];    // batch b0+16
            a0 += w.x * xa.x + w.y * xa.y + w.z * xa.z + w.w * xa.w;
            a1 += w.x * xb.x + w.y * xb.y + w.z * xb.z + w.w * xb.w;
        }
        acc0[k] = a0; acc1[k] = a1;
    }

    // ---- epilogue: round-1 line-clustered atomics ----
    #pragma unroll
    for (int k = 0; k < 4; ++k) {
        int r = (st0[k] << 4) + j;
        unsafeAtomicAdd(&out[ b0       * SIZE + r], acc0[k]);
        unsafeAtomicAdd(&out[(b0 + 16) * SIZE + r], acc1[k]);
    }
}

extern "C" void kernel_launch(void* const* d_in, const int* in_sizes, int n_in,
                              void* d_out, int out_size, void* d_ws, size_t ws_size,
                              hipStream_t stream) {
    const float* x   = (const float*)d_in[0];
    const float* wm  = (const float*)d_in[1];
    const float* wlv = (const float*)d_in[2];
    const float* bm  = (const float*)d_in[3];
    const float* blv = (const float*)d_in[4];
    const float* eb  = (const float*)d_in[5];
    const int* rows  = (const int*)d_in[6];
    const int* cols  = (const int*)d_in[7];
    // NOTE: argument order must match setup_inputs dict order:
    // x, weight_mean, weight_log_var, b_mean, b_log_var, eps_w, eps_b, rows, cols
    (void)eb; (void)rows; (void)cols;
    const float* ew_  = (const float*)d_in[5];
    const float* eb_  = (const float*)d_in[6];
    const int* rows_  = (const int*)d_in[7];
    const int* cols_  = (const int*)d_in[8];
    float* out = (float*)d_out;

    init_out_kernel<<<dim3((SIZE + 255) / 256, BB), 256, 0, stream>>>(bm, blv, eb_, out);
    edge_kernel<<<EG / 4, 256, 0, stream>>>(wm, wlv, ew_, x, rows_, cols_, out);
}